// Round 4
// baseline (211.719 us; speedup 1.0000x reference)
//
#include <hip/hip_runtime.h>
#include <hip/hip_bf16.h>

// 3D bilateral filter, radius 2 (125 taps), input (2,1,128,128,128) f32.
// v4: range weight via 1024-entry LDS lookup table indexed by quantized |d|
// instead of v_exp_f32 per tap. v3 showed ~30 VALU-busy cycles/tap with only
// 5 regular VALU ops -> v_exp_f32 occupies the VALU pipe ~16-20 cyc/wave64.
// The gather moves that cost to the DS pipe (overlaps with VALU across waves).
// tbl[1023] = 0 exactly: cvt_u32 saturation + min-clamp maps the OOB sentinel
// (|d| ~ 1e18) and far-range taps to weight 0 == the reference validity mask.
// Spatial weight = wx(dx) * wyz(dy,dz): one exp per ROW (25/thread), wx folded
// into 3 per-row constants.

#define RADIUS 2
#define N 128
#define TX 16
#define TY 8
#define TZ 8
#define PITCH (TX + 2 * RADIUS)      // 20 floats per row (16B-aligned rows)
#define LYD (TY + 2 * RADIUS)        // 12
#define LZD (TZ + 2 * RADIUS)        // 12
#define LDS_SIZE (PITCH * LYD * LZD) // 2880 floats
#define TBL_N 1024

#if defined(__has_builtin)
#if __has_builtin(__builtin_amdgcn_exp2f)
#define EXP2(x) __builtin_amdgcn_exp2f(x)
#endif
#endif
#ifndef EXP2
#define EXP2(x) __expf((x) * 0.6931471805599453f)
#endif

#define LOG2E 1.4426950408889634f
#define BIG 1.0e18f

__global__ __launch_bounds__(256, 4) void bilateral3d_kernel(
    const float* __restrict__ in, const float* __restrict__ p_sx,
    const float* __restrict__ p_sy, const float* __restrict__ p_sz,
    const float* __restrict__ p_cs, float* __restrict__ out) {
  __shared__ float s[LDS_SIZE];
  __shared__ float tbl[TBL_N];

  const int tid = threadIdx.x;
  const int x0 = blockIdx.x * TX;
  const int y0 = blockIdx.y * TY;
  const int zb = blockIdx.z;  // low 4 bits = z-tile, bit 4 = batch
  const int z0 = (zb & 15) * TZ;
  const int b = zb >> 4;

  const float sxv = p_sx[0], syv = p_sy[0], szv = p_sz[0], csv = p_cs[0];
  const float AX = LOG2E / (2.0f * sxv * sxv);
  const float AY = LOG2E / (2.0f * syv * syv);
  const float AZ = LOG2E / (2.0f * szv * szv);
  const float AC = LOG2E / (2.0f * csv * csv);  // exp2 units

  // range-table domain: weight ~2^-33 at |d| = DMAX; entry 1023 forced to 0
  const float DMAX = 6.782f * csv;
  const float DELTA = DMAX / (float)(TBL_N - 1);
  const float SCALE = 1.0f / DELTA;

  // --- fill range table (4 entries/thread) ---
  for (int q = tid; q < TBL_N; q += 256) {
    float dq = (float)q * DELTA;
    float v = (q == TBL_N - 1) ? 0.0f : EXP2(-(AC * dq * dq));
    tbl[q] = v;
  }

  const float* vol = in + (size_t)b * (N * N * N);

  // --- stage 20x12x12 halo tile (OOB -> sentinel) ---
  for (int i = tid; i < LDS_SIZE; i += 256) {
    int lx = i % PITCH;
    int t = i / PITCH;
    int ly = t % LYD;
    int lz = t / LYD;
    int gx = x0 + lx - RADIUS;
    int gy = y0 + ly - RADIUS;
    int gz = z0 + lz - RADIUS;
    float v = BIG;
    if ((unsigned)gx < N && (unsigned)gy < N && (unsigned)gz < N)
      v = vol[((size_t)gz * N + gy) * N + gx];
    s[i] = v;
  }
  __syncthreads();

  const int tx = tid & 3;         // x-group: voxels x0+4tx .. x0+4tx+3
  const int ty = (tid >> 2) & 7;
  const int tz = tid >> 5;

  const float WX1 = EXP2(-AX);          // spatial x-factor, |dx|=1
  const float WX2 = EXP2(-(4.0f * AX)); // |dx|=2

  const int xw = 4 * tx;  // word offset within row of this thread's tap window

  // center values: words [xw+2 .. xw+5] of the (dz=0,dy=0) row
  const int cbase = ((tz + RADIUS) * LYD + (ty + RADIUS)) * PITCH + xw;
  const float4 CA = *(const float4*)&s[cbase];
  const float4 CB = *(const float4*)&s[cbase + 4];
  const float xc0 = CA.z, xc1 = CA.w, xc2 = CB.x, xc3 = CB.y;

  float n0 = 0, n1 = 0, n2 = 0, n3 = 0;
  float e0 = 0, e1 = 0, e2 = 0, e3 = 0;  // denominators

  // range weight via LDS gather; spatial weight WXR premultiplied per row
#define TAP(XC, FV, WXR, NN, DD)                   \
  {                                                \
    float _d = (XC) - (FV);                        \
    float _if = fmaf(fabsf(_d), SCALE, 0.49f);     \
    unsigned _q = (unsigned)_if;                   \
    _q = _q > (TBL_N - 1u) ? (TBL_N - 1u) : _q;    \
    float _w = tbl[_q] * (WXR);                    \
    DD += _w;                                      \
    NN = fmaf(_w, (FV), NN);                       \
  }

#pragma unroll 1
  for (int dz = -RADIUS; dz <= RADIUS; ++dz) {
    const float pz = AZ * (float)(dz * dz);
    const int zrow = (tz + RADIUS + dz) * LYD;
#pragma unroll
    for (int dy = -RADIUS; dy <= RADIUS; ++dy) {
      const float wyz = EXP2(-(pz + AY * (float)(dy * dy)));
      const float wr1 = wyz * WX1;  // |dx| = 1
      const float wr2 = wyz * WX2;  // |dx| = 2
      const int rb = (zrow + (ty + RADIUS + dy)) * PITCH + xw;
      const float4 A = *(const float4*)&s[rb];
      const float4 B = *(const float4*)&s[rb + 4];
      const float f0 = A.x, f1 = A.y, f2 = A.z, f3 = A.w;
      const float f4 = B.x, f5 = B.y, f6 = B.z, f7 = B.w;

      // dx = -2
      TAP(xc0, f0, wr2, n0, e0)
      TAP(xc1, f1, wr2, n1, e1)
      TAP(xc2, f2, wr2, n2, e2)
      TAP(xc3, f3, wr2, n3, e3)
      // dx = -1
      TAP(xc0, f1, wr1, n0, e0)
      TAP(xc1, f2, wr1, n1, e1)
      TAP(xc2, f3, wr1, n2, e2)
      TAP(xc3, f4, wr1, n3, e3)
      // dx = 0
      TAP(xc0, f2, wyz, n0, e0)
      TAP(xc1, f3, wyz, n1, e1)
      TAP(xc2, f4, wyz, n2, e2)
      TAP(xc3, f5, wyz, n3, e3)
      // dx = +1
      TAP(xc0, f3, wr1, n0, e0)
      TAP(xc1, f4, wr1, n1, e1)
      TAP(xc2, f5, wr1, n2, e2)
      TAP(xc3, f6, wr1, n3, e3)
      // dx = +2
      TAP(xc0, f4, wr2, n0, e0)
      TAP(xc1, f5, wr2, n1, e1)
      TAP(xc2, f6, wr2, n2, e2)
      TAP(xc3, f7, wr2, n3, e3)
    }
  }

  float4 r;
  r.x = n0 / e0;
  r.y = n1 / e1;
  r.z = n2 / e2;
  r.w = n3 / e3;

  const int gz = z0 + tz, gy = y0 + ty;
  *(float4*)&out[(((size_t)b * N + gz) * N + gy) * N + (x0 + xw)] = r;
}

extern "C" void kernel_launch(void* const* d_in, const int* in_sizes, int n_in,
                              void* d_out, int out_size, void* d_ws, size_t ws_size,
                              hipStream_t stream) {
  const float* in = (const float*)d_in[0];
  const float* sx = (const float*)d_in[1];
  const float* sy = (const float*)d_in[2];
  const float* sz = (const float*)d_in[3];
  const float* cs = (const float*)d_in[4];
  float* out = (float*)d_out;

  dim3 grid(N / TX, N / TY, (N / TZ) * 2);  // 8 x 16 x 32
  bilateral3d_kernel<<<grid, 256, 0, stream>>>(in, sx, sy, sz, cs, out);
}

// Round 5
// 146.528 us; speedup vs baseline: 1.4449x; 1.4449x over previous
//
#include <hip/hip_runtime.h>
#include <hip/hip_bf16.h>

// 3D bilateral filter, radius 2 (125 taps), input (2,1,128,128,128) f32.
// v5: v3 shell (4 voxels/thread, 20x12x12 LDS tile, 8 acc chains) with the
// per-tap v_exp_f32 replaced by a Schraudolph bit-trick exp2:
//   w = asfloat((uint)(2^23 * e + 127*2^23)), e = -(spatial + ac*d^2) in log2
// One FMA + one saturating v_cvt_u32_f32 per tap (f<0 or -inf -> 0), which
// also implements the OOB mask: sentinel d~1e18 -> fma overflows to -inf ->
// w = +0.0 exactly. The global 2^-s scale of the trick cancels in num/den;
// residual error is the mantissa-linear spread (max ~3% rel on weights).
// v3 evidence: ~30 VALU-busy cyc/tap, only 10 from plain VALU -> v_exp_f32
// occupied the issue stream ~20 cyc/wave64. This TAP is 6 plain VALU = 12 cyc.
// v4 evidence: LDS-gather LUT saturates the DS pipe (5.4e7 conflict cycles) —
// exp must be removed with VALU ops, not DS ops.

#define RADIUS 2
#define N 128
#define TX 16
#define TY 8
#define TZ 8
#define PITCH (TX + 2 * RADIUS)      // 20 floats per row (16B-aligned rows)
#define LYD (TY + 2 * RADIUS)        // 12
#define LZD (TZ + 2 * RADIUS)        // 12
#define LDS_SIZE (PITCH * LYD * LZD) // 2880 floats = 11.25 KB

#define LOG2E 1.4426950408889634f
#define BIG 1.0e18f
#define EXP2_SCALE 8388608.0f        // 2^23
#define EXP2_BIAS 1065353216.0f      // 127 * 2^23  (asfloat -> 1.0f when e=0)

__global__ __launch_bounds__(256, 4) void bilateral3d_kernel(
    const float* __restrict__ in, const float* __restrict__ p_sx,
    const float* __restrict__ p_sy, const float* __restrict__ p_sz,
    const float* __restrict__ p_cs, float* __restrict__ out) {
  __shared__ float s[LDS_SIZE];

  const int tid = threadIdx.x;
  const int x0 = blockIdx.x * TX;
  const int y0 = blockIdx.y * TY;
  const int zb = blockIdx.z;  // low 4 bits = z-tile, bit 4 = batch
  const int z0 = (zb & 15) * TZ;
  const int b = zb >> 4;

  const float* vol = in + (size_t)b * (N * N * N);

  // --- stage 20x12x12 halo tile (OOB -> sentinel) ---
  for (int i = tid; i < LDS_SIZE; i += 256) {
    int lx = i % PITCH;
    int t = i / PITCH;
    int ly = t % LYD;
    int lz = t / LYD;
    int gx = x0 + lx - RADIUS;
    int gy = y0 + ly - RADIUS;
    int gz = z0 + lz - RADIUS;
    float v = BIG;
    if ((unsigned)gx < N && (unsigned)gy < N && (unsigned)gz < N)
      v = vol[((size_t)gz * N + gy) * N + gx];
    s[i] = v;
  }
  __syncthreads();

  const int tx = tid & 3;         // x-group: voxels x0+4tx .. x0+4tx+3
  const int ty = (tid >> 2) & 7;
  const int tz = tid >> 5;

  // coefficients in exp2 units, pre-scaled by 2^23 for the bit-trick
  const float sxv = p_sx[0], syv = p_sy[0], szv = p_sz[0], csv = p_cs[0];
  const float AX2 = EXP2_SCALE * LOG2E / (2.0f * sxv * sxv);
  const float AY2 = EXP2_SCALE * LOG2E / (2.0f * syv * syv);
  const float AZ2 = EXP2_SCALE * LOG2E / (2.0f * szv * szv);
  const float NAC2 = -(EXP2_SCALE * LOG2E) / (2.0f * csv * csv);
  const float AX2_4 = 4.0f * AX2;

  const int xw = 4 * tx;  // word offset within row of this thread's tap window

  // center values: words [xw+2 .. xw+5] of the (dz=0,dy=0) row
  const int cbase = ((tz + RADIUS) * LYD + (ty + RADIUS)) * PITCH + xw;
  const float4 CA = *(const float4*)&s[cbase];
  const float4 CB = *(const float4*)&s[cbase + 4];
  const float xc0 = CA.z, xc1 = CA.w, xc2 = CB.x, xc3 = CB.y;

  float n0 = 0, n1 = 0, n2 = 0, n3 = 0;
  float e0 = 0, e1 = 0, e2 = 0, e3 = 0;  // denominators

  // Schraudolph tap: one FMA + one saturating cvt; CC carries spatial + bias
#define TAP(XC, FV, CC, NN, DD)                          \
  {                                                      \
    float _d = (XC) - (FV);                              \
    float _f = fmaf(_d * _d, NAC2, (CC));                \
    unsigned _q;                                         \
    asm("v_cvt_u32_f32 %0, %1" : "=v"(_q) : "v"(_f));    \
    float _w = __uint_as_float(_q);                      \
    DD += _w;                                            \
    NN = fmaf(_w, (FV), NN);                             \
  }

#pragma unroll 1
  for (int dz = -RADIUS; dz <= RADIUS; ++dz) {
    const float pz2 = AZ2 * (float)(dz * dz);
    const int zrow = (tz + RADIUS + dz) * LYD;
#pragma unroll
    for (int dy = -RADIUS; dy <= RADIUS; ++dy) {
      // row constant: bias - spatial(dz,dy), then fold |dx| classes
      const float cc0 = EXP2_BIAS - (pz2 + AY2 * (float)(dy * dy));
      const float cm1 = cc0 - AX2;    // |dx| = 1
      const float cm4 = cc0 - AX2_4;  // |dx| = 2
      const int rb = (zrow + (ty + RADIUS + dy)) * PITCH + xw;
      const float4 A = *(const float4*)&s[rb];
      const float4 B = *(const float4*)&s[rb + 4];
      const float f0 = A.x, f1 = A.y, f2 = A.z, f3 = A.w;
      const float f4 = B.x, f5 = B.y, f6 = B.z, f7 = B.w;

      // dx = -2
      TAP(xc0, f0, cm4, n0, e0)
      TAP(xc1, f1, cm4, n1, e1)
      TAP(xc2, f2, cm4, n2, e2)
      TAP(xc3, f3, cm4, n3, e3)
      // dx = -1
      TAP(xc0, f1, cm1, n0, e0)
      TAP(xc1, f2, cm1, n1, e1)
      TAP(xc2, f3, cm1, n2, e2)
      TAP(xc3, f4, cm1, n3, e3)
      // dx = 0
      TAP(xc0, f2, cc0, n0, e0)
      TAP(xc1, f3, cc0, n1, e1)
      TAP(xc2, f4, cc0, n2, e2)
      TAP(xc3, f5, cc0, n3, e3)
      // dx = +1
      TAP(xc0, f3, cm1, n0, e0)
      TAP(xc1, f4, cm1, n1, e1)
      TAP(xc2, f5, cm1, n2, e2)
      TAP(xc3, f6, cm1, n3, e3)
      // dx = +2
      TAP(xc0, f4, cm4, n0, e0)
      TAP(xc1, f5, cm4, n1, e1)
      TAP(xc2, f6, cm4, n2, e2)
      TAP(xc3, f7, cm4, n3, e3)
    }
  }

  float4 r;
  r.x = n0 / e0;
  r.y = n1 / e1;
  r.z = n2 / e2;
  r.w = n3 / e3;

  const int gz = z0 + tz, gy = y0 + ty;
  *(float4*)&out[(((size_t)b * N + gz) * N + gy) * N + (x0 + xw)] = r;
}

extern "C" void kernel_launch(void* const* d_in, const int* in_sizes, int n_in,
                              void* d_out, int out_size, void* d_ws, size_t ws_size,
                              hipStream_t stream) {
  const float* in = (const float*)d_in[0];
  const float* sx = (const float*)d_in[1];
  const float* sy = (const float*)d_in[2];
  const float* sz = (const float*)d_in[3];
  const float* cs = (const float*)d_in[4];
  float* out = (float*)d_out;

  dim3 grid(N / TX, N / TY, (N / TZ) * 2);  // 8 x 16 x 32
  bilateral3d_kernel<<<grid, 256, 0, stream>>>(in, sx, sy, sz, cs, out);
}